// Round 11
// baseline (2961.398 us; speedup 1.0000x reference)
//
#include <hip/hip_runtime.h>
#include <hip/hip_fp16.h>
#include <math.h>

#define TT 256
#define HC 128
#define HB 64
#define NL 8

// ---- ws layout (floats) ----
#define WS_WGT 0
#define WS_PB  65536
#define WS_PG  66048
#define WS_GP  66560
#define WS_BP  67584

#define ZROWS_LDS 20          // pair-rows of z kept in LDS
#define ZROWS_REG (64 - ZROWS_LDS)

__device__ __forceinline__ float fast_tanh(float x) {
    float e = __expf(2.f * fabsf(x));
    float r = 1.f - 2.f / (1.f + e);
    return copysignf(r, x);
}
__device__ __forceinline__ float fast_sig(float x) {
    return 1.f / (1.f + __expf(-x));
}
__device__ __forceinline__ unsigned packh2(float a, float b) {
    __half2 h = __floats2half2_rn(a, b);
    return __builtin_bit_cast(unsigned, h);
}
__device__ __forceinline__ float loh(unsigned u) {
    return __low2float(__builtin_bit_cast(__half2, u));
}
__device__ __forceinline__ float hih(unsigned u) {
    return __high2float(__builtin_bit_cast(__half2, u));
}

__global__ __launch_bounds__(128)
void tcn_setup(const float* __restrict__ pw_in, const float* __restrict__ gn_g,
               const float* __restrict__ gn_b, float* __restrict__ ws) {
    int i = blockIdx.x;      // layer
    int tid = threadIdx.x;   // 128 threads
    float* WgT = ws + WS_WGT;
    float* Pb  = ws + WS_PB;
    float* Pg  = ws + WS_PG;
    float* Gp  = ws + WS_GP;
    float* Bp  = ws + WS_BP;

    float g = (i == 0) ? 1.f : gn_g[(i - 1) * HC + tid];
    float bb = (i == 0) ? 0.f : gn_b[(i - 1) * HC + tid];
    Gp[i * HC + tid] = g;
    Bp[i * HC + tid] = bb;
    for (int o = 0; o < HB; o++)
        WgT[(i * HC + tid) * HB + o] = pw_in[((size_t)i * HB + o) * HC + tid] * g;

    if (tid < HB) {
        float pb = 0.f, pg = 0.f;
        for (int c = 0; c < HC; c++) {
            float w = pw_in[((size_t)i * HB + tid) * HC + c];
            float gc = (i == 0) ? 1.f : gn_g[(i - 1) * HC + c];
            float bc = (i == 0) ? 0.f : gn_b[(i - 1) * HC + c];
            pb += bc * w;
            pg += gc * w;
        }
        Pb[i * HB + tid] = pb;
        Pg[i * HB + tid] = pg;
    }
}

// STATIC LDS — total 30976 B so TWO blocks fit the effective ~64KB
// co-residency pool (measured: 23KB->2 blocks, 31KB->2 blocks, 62KB->1):
//   zl    uint [20][256]  20480  fp16 pair (ch 2p,2p+1), t-major
//   haloU uint [48][33]    6336  packed (u[k],u[32+k]); wave3 never publishes
//         head bufs (wbuf/hbuf/qbuf, 1280B) union halo rows (dead by head)
//   sLast f32  [8][128]    4096
//   red   f32  [16]          64
// NOTE: plain __launch_bounds__(256) — any min-waves hint (2 or 3) makes the
// allocator cap VGPRs at 128/84 and spill gigabytes (rounds 4/5/6/10);
// unhinted it picks 132-168 spill-free (rounds 7/8/9).
__global__ __launch_bounds__(256)
void tcn_main(const float* __restrict__ x, const float* __restrict__ in_w,
              const float* __restrict__ in_b, const float* __restrict__ dw_w,
              const float* __restrict__ pw_out, const float* __restrict__ skip_w,
              const float* __restrict__ ln_g, const float* __restrict__ ln_b,
              const float* __restrict__ h1_w, const float* __restrict__ h1_b,
              const float* __restrict__ h2_w, const float* __restrict__ h2_b,
              const float* __restrict__ ws, float* __restrict__ out) {
    __shared__ unsigned zl[ZROWS_LDS * 256];
    __shared__ unsigned haloU[48 * 33];
    __shared__ float sLast[NL * HC];
    __shared__ float red[16];
    // head buffers union the halo (halo fully dead after last conv)
    float* wbuf = (float*)haloU;         // 64 floats
    float* hbuf = wbuf + 64;             // 128 floats
    float* qbuf = hbuf + 128;            // 128 floats (320 floats <= 1584 avail)

    const float* WgT = ws + WS_WGT;
    const float* Pb  = ws + WS_PB;
    const float* Pg  = ws + WS_PG;
    const float* Gp  = ws + WS_GP;
    const float* Bp  = ws + WS_BP;

    const int t = threadIdx.x;     // time index, 0..255
    const int bn = blockIdx.x;     // sample
    const int b = bn >> 7, n = bn & 127;
    const int lane = t & 63;
    const int wv = t >> 6;

    // channels 2*ZROWS_LDS..127 live in registers (44 packed fp16 pairs)
    unsigned zr[ZROWS_REG];

    // ---------- phase 0: input projection  z[c] = x[b,t,n,:] @ in_w + in_b
    {
        const float* xp = x + (((size_t)b * TT + t) * 128 + n) * 16;
        float xr[16];
#pragma unroll
        for (int d = 0; d < 16; d++) xr[d] = xp[d];
#pragma unroll
        for (int c = 0; c < HC; c += 2) {
            float a0 = in_b[c], a1 = in_b[c + 1];
#pragma unroll
            for (int d = 0; d < 16; d++) {
                a0 = fmaf(xr[d], in_w[d * HC + c], a0);
                a1 = fmaf(xr[d], in_w[d * HC + c + 1], a1);
            }
            const int cp = c >> 1;
            if (cp < ZROWS_LDS) zl[cp * TT + t]  = packh2(a0, a1);
            else                zr[cp - ZROWS_LDS] = packh2(a0, a1);
        }
    }

    float m_s = 0.f, r_s = 1.f;   // deferred groupnorm scalars

#pragma unroll 1
    for (int L = 0; L < NL; L++) {
        const int dil = 1 << (L & 3);
        const bool lastL = (L == NL - 1);
        const bool active = (!lastL) || (wv == 3);

        // ---------- u-phase (single pass, 64 accumulators), result packed:
        // pu[k] = (u[k], u[32+k])
        unsigned pu[32];
        if (active) {
            const float* W = WgT + (size_t)L * HC * HB;
            float acc[HB];
#pragma unroll
            for (int o = 0; o < HB; o++) acc[o] = 0.f;
#pragma unroll 2
            for (int p = 0; p < ZROWS_LDS; p++) {
                unsigned pz = zl[p * TT + t];
                float z0 = loh(pz), z1 = hih(pz);
                const float* w0 = W + (2 * p) * HB;
                const float* w1 = w0 + HB;
#pragma unroll
                for (int o = 0; o < HB; o++)
                    acc[o] = fmaf(z1, w1[o], fmaf(z0, w0[o], acc[o]));
            }
#pragma unroll
            for (int p = ZROWS_LDS; p < 64; p++) {
                unsigned pz = zr[p - ZROWS_LDS];
                float z0 = loh(pz), z1 = hih(pz);
                const float* w0 = W + (2 * p) * HB;
                const float* w1 = w0 + HB;
#pragma unroll
                for (int o = 0; o < HB; o++)
                    acc[o] = fmaf(z1, w1[o], fmaf(z0, w0[o], acc[o]));
            }
            float mr = m_s * r_s;
#pragma unroll
            for (int k = 0; k < 32; k++) {
                float ua = fmaf(r_s, acc[k],      Pb[L * HB + k]      - mr * Pg[L * HB + k]);
                float ub = fmaf(r_s, acc[32 + k], Pb[L * HB + 32 + k] - mr * Pg[L * HB + 32 + k]);
                pu[k] = packh2(ua, ub);
            }
            // halo publish: waves 0..2 rows feed the next wave's lookback;
            // wave 3 has no successor (its rows were never read) -> skip
            if (wv < 3 && lane >= 48) {
                int hr = wv * 16 + (lane - 48);
#pragma unroll
                for (int k = 0; k < 32; k++) haloU[hr * 33 + k] = pu[k];
            }
        }
        __syncthreads();   // B1: halo ready

        // ---------- conv + gating (round-5-verified packed mapping)
        // f[2k],f[2k+1] use lo(pu[k]); gate[2k],gate[2k+1] use hi(pu[k])
        float w_[HB];
        if (active) {
            const float* dwl = dw_w + (size_t)L * 128 * 3;
            const int d1 = dil, d2 = 2 * dil;
#pragma unroll
            for (int k = 0; k < 32; k++) {
                unsigned pk = pu[k];
                unsigned p1 = __shfl_up(pk, d1);
                unsigned p2 = __shfl_up(pk, d2);
                if (lane < d1) {
                    int tau = t - d1;
                    p1 = (tau < 0) ? 0u : haloU[((tau >> 6) * 16 + (tau & 63) - 48) * 33 + k];
                }
                if (lane < d2) {
                    int tau = t - d2;
                    p2 = (tau < 0) ? 0u : haloU[((tau >> 6) * 16 + (tau & 63) - 48) * 33 + k];
                }
                float uf = loh(pk), ug = hih(pk);
                float m1f = loh(p1), m1g = hih(p1);
                float m2f = loh(p2), m2g = hih(p2);
                float f0 = m2f * dwl[(2 * k) * 3 + 0] + m1f * dwl[(2 * k) * 3 + 1] + uf * dwl[(2 * k) * 3 + 2];
                float f1 = m2f * dwl[(2 * k + 1) * 3 + 0] + m1f * dwl[(2 * k + 1) * 3 + 1] + uf * dwl[(2 * k + 1) * 3 + 2];
                float g0 = m2g * dwl[(64 + 2 * k) * 3 + 0] + m1g * dwl[(64 + 2 * k) * 3 + 1] + ug * dwl[(64 + 2 * k) * 3 + 2];
                float g1 = m2g * dwl[(64 + 2 * k + 1) * 3 + 0] + m1g * dwl[(64 + 2 * k + 1) * 3 + 1] + ug * dwl[(64 + 2 * k + 1) * 3 + 2];
                w_[2 * k]     = fast_tanh(f0) * fast_sig(g0);
                w_[2 * k + 1] = fast_tanh(f1) * fast_sig(g1);
            }
        }

        if (!lastL) {
            // ---------- s-phase: s_feat, residual update (deferred GN), stats
            float s1 = 0.f, s2 = 0.f;
            const float* Po = pw_out + (size_t)L * HC * HB;
            const float mr = m_s * r_s;
            const float* gp = Gp + L * HC;
            const float* bp = Bp + L * HC;
            // channels in LDS-resident pairs
#pragma unroll 2
            for (int cp = 0; cp < ZROWS_LDS; cp++) {
                const int c = 2 * cp;
                float a0 = 0.f, b0 = 0.f, a1 = 0.f, b1 = 0.f;
                const float* p0 = Po + c * HB;
                const float* p1 = p0 + HB;
#pragma unroll
                for (int cc = 0; cc < 32; cc++) {
                    a0 = fmaf(w_[2 * cc],     p0[2 * cc],     a0);
                    b0 = fmaf(w_[2 * cc + 1], p0[2 * cc + 1], b0);
                    a1 = fmaf(w_[2 * cc],     p1[2 * cc],     a1);
                    b1 = fmaf(w_[2 * cc + 1], p1[2 * cc + 1], b1);
                }
                float acc0 = a0 + b0, acc1 = a1 + b1;
                if (t == TT - 1) {
                    sLast[L * HC + c] = acc0;
                    sLast[L * HC + c + 1] = acc1;
                }
                unsigned pz = zl[cp * TT + t];
                float zo0 = loh(pz), zo1 = hih(pz);
                float g0 = gp[c], g1 = gp[c + 1];
                float zn0 = fmaf(zo0, r_s * g0, (bp[c]     - mr * g0) + acc0);
                float zn1 = fmaf(zo1, r_s * g1, (bp[c + 1] - mr * g1) + acc1);
                zl[cp * TT + t] = packh2(zn0, zn1);
                s1 += zn0 + zn1;
                s2 += zn0 * zn0 + zn1 * zn1;
            }
            // channels in register-resident pairs
#pragma unroll
            for (int cp = ZROWS_LDS; cp < 64; cp++) {
                const int c = 2 * cp;
                float a0 = 0.f, b0 = 0.f, a1 = 0.f, b1 = 0.f;
                const float* p0 = Po + c * HB;
                const float* p1 = p0 + HB;
#pragma unroll
                for (int cc = 0; cc < 32; cc++) {
                    a0 = fmaf(w_[2 * cc],     p0[2 * cc],     a0);
                    b0 = fmaf(w_[2 * cc + 1], p0[2 * cc + 1], b0);
                    a1 = fmaf(w_[2 * cc],     p1[2 * cc],     a1);
                    b1 = fmaf(w_[2 * cc + 1], p1[2 * cc + 1], b1);
                }
                float acc0 = a0 + b0, acc1 = a1 + b1;
                if (t == TT - 1) {
                    sLast[L * HC + c] = acc0;
                    sLast[L * HC + c + 1] = acc1;
                }
                unsigned pz = zr[cp - ZROWS_LDS];
                float zo0 = loh(pz), zo1 = hih(pz);
                float g0 = gp[c], g1 = gp[c + 1];
                float zn0 = fmaf(zo0, r_s * g0, (bp[c]     - mr * g0) + acc0);
                float zn1 = fmaf(zo1, r_s * g1, (bp[c + 1] - mr * g1) + acc1);
                zr[cp - ZROWS_LDS] = packh2(zn0, zn1);
                s1 += zn0 + zn1;
                s2 += zn0 * zn0 + zn1 * zn1;
            }
#pragma unroll
            for (int off = 32; off; off >>= 1) {
                s1 += __shfl_xor(s1, off);
                s2 += __shfl_xor(s2, off);
            }
            if (lane == 0) { red[wv * 2] = s1; red[wv * 2 + 1] = s2; }
            __syncthreads();   // B2
            float S1 = red[0] + red[2] + red[4] + red[6];
            float S2 = red[1] + red[3] + red[5] + red[7];
            float mu = S1 * (1.f / 32768.f);
            float var = S2 * (1.f / 32768.f) - mu * mu;
            m_s = mu;
            r_s = rsqrtf(var + 1e-5f);
        } else {
            // last layer: only t==255's gated output matters; parallelize its s-row
            if (t == TT - 1) {
#pragma unroll
                for (int cc = 0; cc < HB; cc++) wbuf[cc] = w_[cc];
            }
            __syncthreads();   // B2: wbuf ready (halo reads all done)
            if (t < HC) {
                const float* pr = pw_out + ((size_t)(NL - 1) * HC + t) * HB;
                float a = 0.f;
                for (int cc = 0; cc < HB; cc++) a = fmaf(wbuf[cc], pr[cc], a);
                sLast[(NL - 1) * HC + t] = a;
            }
            __syncthreads();   // B3: sLast complete
        }
    }

    // ---------- head: h_last = sum_i skip_w[i] @ sLast[i]; LN; MLP
    float hl = 0.f;
    if (t < HC) {
        for (int i = 0; i < NL; i++) {
            const float4* swr = (const float4*)(skip_w + (((size_t)i * HC) + t) * HC);
            const float* sl = sLast + i * HC;
#pragma unroll 4
            for (int c4 = 0; c4 < 32; c4++) {
                float4 sw = swr[c4];
                hl += sw.x * sl[4 * c4] + sw.y * sl[4 * c4 + 1] + sw.z * sl[4 * c4 + 2] + sw.w * sl[4 * c4 + 3];
            }
        }
        hbuf[t] = hl;
    }
    __syncthreads();
    if (t < 64) {
        float v0 = hbuf[t], v1 = hbuf[t + 64];
        float a = v0 + v1, q = v0 * v0 + v1 * v1;
#pragma unroll
        for (int off = 32; off; off >>= 1) {
            a += __shfl_xor(a, off);
            q += __shfl_xor(q, off);
        }
        if (t == 0) {
            float mu = a * (1.f / 128.f);
            red[0] = mu;
            red[1] = rsqrtf(q * (1.f / 128.f) - mu * mu + 1e-5f);
        }
    }
    __syncthreads();
    {
        float mu = red[0], rs = red[1];
        if (t < HC) hbuf[t] = (hl - mu) * rs * ln_g[t] + ln_b[t];
    }
    __syncthreads();
    if (t < HC) {
        float q = h1_b[t];
        for (int c = 0; c < HC; c++) q = fmaf(hbuf[c], h1_w[c * HC + t], q);
        q = 0.5f * q * (1.f + erff(q * 0.70710678118654752f));
        qbuf[t] = q;
    }
    __syncthreads();
    if (t < 24) {
        float o = h2_b[t];
        for (int c = 0; c < HC; c++) o = fmaf(qbuf[c], h2_w[c * 24 + t], o);
        out[((size_t)b * 24 + t) * 128 + n] = o;
    }
}

extern "C" void kernel_launch(void* const* d_in, const int* in_sizes, int n_in,
                              void* d_out, int out_size, void* d_ws, size_t ws_size,
                              hipStream_t stream) {
    const float* x      = (const float*)d_in[0];
    const float* in_w   = (const float*)d_in[1];
    const float* in_b   = (const float*)d_in[2];
    const float* pw_in  = (const float*)d_in[3];
    const float* dw_w   = (const float*)d_in[4];
    const float* pw_out = (const float*)d_in[5];
    const float* gn_g   = (const float*)d_in[6];
    const float* gn_b   = (const float*)d_in[7];
    const float* skip_w = (const float*)d_in[8];
    const float* ln_g   = (const float*)d_in[9];
    const float* ln_b   = (const float*)d_in[10];
    const float* h1_w   = (const float*)d_in[11];
    const float* h1_b   = (const float*)d_in[12];
    const float* h2_w   = (const float*)d_in[13];
    const float* h2_b   = (const float*)d_in[14];
    float* out = (float*)d_out;
    float* ws  = (float*)d_ws;

    tcn_setup<<<NL, 128, 0, stream>>>(pw_in, gn_g, gn_b, ws);

    tcn_main<<<1024, 256, 0, stream>>>(x, in_w, in_b, dw_w, pw_out, skip_w,
                                       ln_g, ln_b, h1_w, h1_b, h2_w, h2_b, ws, out);
}

// Round 12
// 1388.829 us; speedup vs baseline: 2.1323x; 2.1323x over previous
//
#include <hip/hip_runtime.h>
#include <hip/hip_fp16.h>
#include <math.h>

#define TT 256
#define HC 128
#define HB 64
#define NL 8

// ---- ws layout ----
// uint view [0, 65536): packed fp16 weights, 8192 per layer:
//   [L*8192 + p*64 + o]        = (W[2p][o], W[2p+1][o])     u-phase (W = g_prev-folded pw_in^T)
//   [L*8192 + 4096 + c*32 + k] = (Po[c][2k], Po[c][2k+1])   s-phase (Po = pw_out)
// float view: Pb @65536, Pg @66048, Gp @66560, Bp @67584
#define WS_PB  65536
#define WS_PG  66048
#define WS_GP  66560
#define WS_BP  67584

typedef _Float16 h2vec __attribute__((ext_vector_type(2)));

__device__ __forceinline__ float fdot2(unsigned a, unsigned b, float c) {
#if __has_builtin(__builtin_amdgcn_fdot2)
    return __builtin_amdgcn_fdot2(__builtin_bit_cast(h2vec, a),
                                  __builtin_bit_cast(h2vec, b), c, false);
#else
    __half2 ah = __builtin_bit_cast(__half2, a);
    __half2 bh = __builtin_bit_cast(__half2, b);
    c = fmaf(__low2float(ah), __low2float(bh), c);
    return fmaf(__high2float(ah), __high2float(bh), c);
#endif
}

__device__ __forceinline__ float fast_tanh(float x) {
    float e = __expf(2.f * fabsf(x));
    float r = 1.f - 2.f / (1.f + e);
    return copysignf(r, x);
}
__device__ __forceinline__ float fast_sig(float x) {
    return 1.f / (1.f + __expf(-x));
}
__device__ __forceinline__ unsigned packh2(float a, float b) {
    __half2 h = __floats2half2_rn(a, b);
    return __builtin_bit_cast(unsigned, h);
}
__device__ __forceinline__ float loh(unsigned u) {
    return __low2float(__builtin_bit_cast(__half2, u));
}
__device__ __forceinline__ float hih(unsigned u) {
    return __high2float(__builtin_bit_cast(__half2, u));
}

__global__ __launch_bounds__(256)
void tcn_setup(const float* __restrict__ pw_in, const float* __restrict__ pw_out,
               const float* __restrict__ gn_g, const float* __restrict__ gn_b,
               float* __restrict__ ws) {
    const int i = blockIdx.x;      // layer
    const int tid = threadIdx.x;   // 256 threads
    unsigned* WP = (unsigned*)ws;
    float* Pb = ws + WS_PB;
    float* Pg = ws + WS_PG;
    float* Gp = ws + WS_GP;
    float* Bp = ws + WS_BP;

    if (tid < HC) {
        float g  = (i == 0) ? 1.f : gn_g[(i - 1) * HC + tid];
        float bb = (i == 0) ? 0.f : gn_b[(i - 1) * HC + tid];
        Gp[i * HC + tid] = g;
        Bp[i * HC + tid] = bb;
    }
    // u-phase weights: Wp[p*64+o] = (pw_in[i][o][2p]*g[2p], pw_in[i][o][2p+1]*g[2p+1])
    for (int e = tid; e < 4096; e += 256) {
        int p = e >> 6, o = e & 63;
        float g0 = (i == 0) ? 1.f : gn_g[(i - 1) * HC + 2 * p];
        float g1 = (i == 0) ? 1.f : gn_g[(i - 1) * HC + 2 * p + 1];
        float w0 = pw_in[((size_t)i * HB + o) * HC + 2 * p] * g0;
        float w1 = pw_in[((size_t)i * HB + o) * HC + 2 * p + 1] * g1;
        WP[(size_t)i * 8192 + e] = packh2(w0, w1);
    }
    // s-phase weights: Pp[c*32+k] = (pw_out[i][c][2k], pw_out[i][c][2k+1])
    for (int e = tid; e < 4096; e += 256) {
        int c = e >> 5, k = e & 31;
        float w0 = pw_out[((size_t)i * HC + c) * HB + 2 * k];
        float w1 = pw_out[((size_t)i * HC + c) * HB + 2 * k + 1];
        WP[(size_t)i * 8192 + 4096 + e] = packh2(w0, w1);
    }
    if (tid < HB) {
        float pb = 0.f, pg = 0.f;
        for (int c = 0; c < HC; c++) {
            float w = pw_in[((size_t)i * HB + tid) * HC + c];
            float gc = (i == 0) ? 1.f : gn_g[(i - 1) * HC + c];
            float bc = (i == 0) ? 0.f : gn_b[(i - 1) * HC + c];
            pb += bc * w;
            pg += gc * w;
        }
        Pb[i * HB + tid] = pb;
        Pg[i * HB + tid] = pg;
    }
}

// STATIC LDS: wlds 32768 + haloU 6336 + sLast 4096 + red 64 = 43264 B
// (1 block/CU accepted — 2-block residency needs VGPR<=128 which spills;
//  weights-in-LDS instead removes the latency that occupancy was hiding)
__global__ __launch_bounds__(256)
void tcn_main(const float* __restrict__ x, const float* __restrict__ in_w,
              const float* __restrict__ in_b, const float* __restrict__ dw_w,
              const float* __restrict__ pw_out, const float* __restrict__ skip_w,
              const float* __restrict__ ln_g, const float* __restrict__ ln_b,
              const float* __restrict__ h1_w, const float* __restrict__ h1_b,
              const float* __restrict__ h2_w, const float* __restrict__ h2_b,
              const float* __restrict__ ws, float* __restrict__ out) {
    __shared__ unsigned wlds[8192];     // [0,4096) Wp, [4096,8192) Pp for current layer
    __shared__ unsigned haloU[48 * 33]; // packed (u[k],u[32+k]) halo rows
    __shared__ float sLast[NL * HC];
    __shared__ float red[16];
    // head/last-layer buffers union haloU (halo dead by the time they're used)
    unsigned* wb2u = haloU;                   // 32 uints: last-layer packed w2
    float* hbuf = (float*)(haloU + 64);       // 128 floats
    float* qbuf = hbuf + 128;                 // 128 floats

    const float* Pb = ws + WS_PB;
    const float* Pg = ws + WS_PG;
    const float* Gp = ws + WS_GP;
    const float* Bp = ws + WS_BP;
    const unsigned* WP = (const unsigned*)ws;

    const int t = threadIdx.x;     // time index, 0..255
    const int bn = blockIdx.x;     // sample
    const int b = bn >> 7, n = bn & 127;
    const int lane = t & 63;
    const int wv = t >> 6;

    // residual state fully register-resident: z2[p] = (ch 2p, ch 2p+1), fp16
    unsigned z2[64];

    // ---------- phase 0: input projection  z[c] = x[b,t,n,:] @ in_w + in_b
    {
        const float* xp = x + (((size_t)b * TT + t) * 128 + n) * 16;
        float xr[16];
#pragma unroll
        for (int d = 0; d < 16; d++) xr[d] = xp[d];
#pragma unroll
        for (int c = 0; c < HC; c += 2) {
            float a0 = in_b[c], a1 = in_b[c + 1];
#pragma unroll
            for (int d = 0; d < 16; d++) {
                a0 = fmaf(xr[d], in_w[d * HC + c], a0);
                a1 = fmaf(xr[d], in_w[d * HC + c + 1], a1);
            }
            z2[c >> 1] = packh2(a0, a1);
        }
    }

    float m_s = 0.f, r_s = 1.f;   // deferred groupnorm scalars

#pragma unroll 1
    for (int L = 0; L < NL; L++) {
        const int dil = 1 << (L & 3);
        const bool lastL = (L == NL - 1);
        const bool active = (!lastL) || (wv == 3);

        // ---------- stage this layer's weights into LDS (all threads)
        {
            const uint4* src = (const uint4*)(WP + (size_t)L * 8192);
            uint4* dst = (uint4*)wlds;
#pragma unroll
            for (int i = 0; i < 8; i++) dst[t + 256 * i] = src[t + 256 * i];
        }
        __syncthreads();   // B0: weights staged

        // ---------- u-phase: acc[o] = sum_p dot2(z2[p], Wp[p][o]); packed result
        unsigned pu[32];
        if (active) {
            float acc[HB];
#pragma unroll
            for (int o = 0; o < HB; o++) acc[o] = 0.f;
#pragma unroll 2
            for (int p = 0; p < 64; p++) {
                unsigned zq = z2[p];
                const uint4* wrow = (const uint4*)(wlds + p * 64);
#pragma unroll
                for (int o4 = 0; o4 < 16; o4++) {
                    uint4 q = wrow[o4];
                    acc[4 * o4 + 0] = fdot2(zq, q.x, acc[4 * o4 + 0]);
                    acc[4 * o4 + 1] = fdot2(zq, q.y, acc[4 * o4 + 1]);
                    acc[4 * o4 + 2] = fdot2(zq, q.z, acc[4 * o4 + 2]);
                    acc[4 * o4 + 3] = fdot2(zq, q.w, acc[4 * o4 + 3]);
                }
            }
            float mr = m_s * r_s;
#pragma unroll
            for (int k = 0; k < 32; k++) {
                float ua = fmaf(r_s, acc[k],      Pb[L * HB + k]      - mr * Pg[L * HB + k]);
                float ub = fmaf(r_s, acc[32 + k], Pb[L * HB + 32 + k] - mr * Pg[L * HB + 32 + k]);
                pu[k] = packh2(ua, ub);
            }
            // halo publish: waves 0..2 only (wave 3 rows are never read)
            if (wv < 3 && lane >= 48) {
                int hr = wv * 16 + (lane - 48);
#pragma unroll
                for (int k = 0; k < 32; k++) haloU[hr * 33 + k] = pu[k];
            }
        }
        __syncthreads();   // B1: halo ready

        // ---------- conv + gating -> packed w2[k] = (w[2k], w[2k+1])
        unsigned w2[32];
        if (active) {
            const float* dwl = dw_w + (size_t)L * 128 * 3;
            const int d1 = dil, d2 = 2 * dil;
#pragma unroll
            for (int k = 0; k < 32; k++) {
                unsigned pk = pu[k];
                unsigned p1 = __shfl_up(pk, d1);
                unsigned p2 = __shfl_up(pk, d2);
                if (lane < d1) {
                    int tau = t - d1;
                    p1 = (tau < 0) ? 0u : haloU[((tau >> 6) * 16 + (tau & 63) - 48) * 33 + k];
                }
                if (lane < d2) {
                    int tau = t - d2;
                    p2 = (tau < 0) ? 0u : haloU[((tau >> 6) * 16 + (tau & 63) - 48) * 33 + k];
                }
                float uf = loh(pk), ug = hih(pk);
                float m1f = loh(p1), m1g = hih(p1);
                float m2f = loh(p2), m2g = hih(p2);
                float f0 = m2f * dwl[(2 * k) * 3 + 0] + m1f * dwl[(2 * k) * 3 + 1] + uf * dwl[(2 * k) * 3 + 2];
                float f1 = m2f * dwl[(2 * k + 1) * 3 + 0] + m1f * dwl[(2 * k + 1) * 3 + 1] + uf * dwl[(2 * k + 1) * 3 + 2];
                float g0 = m2g * dwl[(64 + 2 * k) * 3 + 0] + m1g * dwl[(64 + 2 * k) * 3 + 1] + ug * dwl[(64 + 2 * k) * 3 + 2];
                float g1 = m2g * dwl[(64 + 2 * k + 1) * 3 + 0] + m1g * dwl[(64 + 2 * k + 1) * 3 + 1] + ug * dwl[(64 + 2 * k + 1) * 3 + 2];
                w2[k] = packh2(fast_tanh(f0) * fast_sig(g0), fast_tanh(f1) * fast_sig(g1));
            }
        }

        if (!lastL) {
            // ---------- s-phase: s_feat via dot2, residual update (deferred GN), stats
            float s1 = 0.f, s2 = 0.f;
            const float mr = m_s * r_s;
            const float* gp = Gp + L * HC;
            const float* bp = Bp + L * HC;
#pragma unroll 2
            for (int cp = 0; cp < 64; cp++) {
                const int c = 2 * cp;
                float a0 = 0.f, a1 = 0.f;
                const uint4* r0 = (const uint4*)(wlds + 4096 + c * 32);
                const uint4* r1 = (const uint4*)(wlds + 4096 + (c + 1) * 32);
#pragma unroll
                for (int k4 = 0; k4 < 8; k4++) {
                    uint4 q0 = r0[k4], q1 = r1[k4];
                    a0 = fdot2(w2[4 * k4 + 0], q0.x, a0);
                    a0 = fdot2(w2[4 * k4 + 1], q0.y, a0);
                    a0 = fdot2(w2[4 * k4 + 2], q0.z, a0);
                    a0 = fdot2(w2[4 * k4 + 3], q0.w, a0);
                    a1 = fdot2(w2[4 * k4 + 0], q1.x, a1);
                    a1 = fdot2(w2[4 * k4 + 1], q1.y, a1);
                    a1 = fdot2(w2[4 * k4 + 2], q1.z, a1);
                    a1 = fdot2(w2[4 * k4 + 3], q1.w, a1);
                }
                if (t == TT - 1) {
                    sLast[L * HC + c] = a0;
                    sLast[L * HC + c + 1] = a1;
                }
                unsigned pz = z2[cp];
                float zo0 = loh(pz), zo1 = hih(pz);
                float g0 = gp[c], g1 = gp[c + 1];
                float zn0 = fmaf(zo0, r_s * g0, (bp[c]     - mr * g0) + a0);
                float zn1 = fmaf(zo1, r_s * g1, (bp[c + 1] - mr * g1) + a1);
                z2[cp] = packh2(zn0, zn1);
                s1 += zn0 + zn1;
                s2 += zn0 * zn0 + zn1 * zn1;
            }
#pragma unroll
            for (int off = 32; off; off >>= 1) {
                s1 += __shfl_xor(s1, off);
                s2 += __shfl_xor(s2, off);
            }
            if (lane == 0) { red[wv * 2] = s1; red[wv * 2 + 1] = s2; }
            __syncthreads();   // B2
            float S1 = red[0] + red[2] + red[4] + red[6];
            float S2 = red[1] + red[3] + red[5] + red[7];
            float mu = S1 * (1.f / 32768.f);
            float var = S2 * (1.f / 32768.f) - mu * mu;
            m_s = mu;
            r_s = rsqrtf(var + 1e-5f);
        } else {
            // last layer: only t==255's gated output matters; parallelize its s-row
            // (safe halo reuse: in last layer only wave 3 ran conv, reading halo
            //  rows 32..47; wb2u occupies rows 0..1)
            if (t == TT - 1) {
#pragma unroll
                for (int k = 0; k < 32; k++) wb2u[k] = w2[k];
            }
            __syncthreads();   // B2: wb2u ready
            if (t < HC) {
                float a = 0.f;
#pragma unroll
                for (int k = 0; k < 32; k++)
                    a = fdot2(wb2u[k], wlds[4096 + t * 32 + k], a);
                sLast[(NL - 1) * HC + t] = a;
            }
            __syncthreads();   // B3: sLast complete
        }
    }

    // ---------- head: h_last = sum_i skip_w[i] @ sLast[i]; LN; MLP
    float hl = 0.f;
    if (t < HC) {
        for (int i = 0; i < NL; i++) {
            const float4* swr = (const float4*)(skip_w + (((size_t)i * HC) + t) * HC);
            const float* sl = sLast + i * HC;
#pragma unroll 4
            for (int c4 = 0; c4 < 32; c4++) {
                float4 sw = swr[c4];
                hl += sw.x * sl[4 * c4] + sw.y * sl[4 * c4 + 1] + sw.z * sl[4 * c4 + 2] + sw.w * sl[4 * c4 + 3];
            }
        }
        hbuf[t] = hl;
    }
    __syncthreads();
    if (t < 64) {
        float v0 = hbuf[t], v1 = hbuf[t + 64];
        float a = v0 + v1, q = v0 * v0 + v1 * v1;
#pragma unroll
        for (int off = 32; off; off >>= 1) {
            a += __shfl_xor(a, off);
            q += __shfl_xor(q, off);
        }
        if (t == 0) {
            float mu = a * (1.f / 128.f);
            red[0] = mu;
            red[1] = rsqrtf(q * (1.f / 128.f) - mu * mu + 1e-5f);
        }
    }
    __syncthreads();
    {
        float mu = red[0], rs = red[1];
        if (t < HC) hbuf[t] = (hl - mu) * rs * ln_g[t] + ln_b[t];
    }
    __syncthreads();
    if (t < HC) {
        float q = h1_b[t];
        for (int c = 0; c < HC; c++) q = fmaf(hbuf[c], h1_w[c * HC + t], q);
        q = 0.5f * q * (1.f + erff(q * 0.70710678118654752f));
        qbuf[t] = q;
    }
    __syncthreads();
    if (t < 24) {
        float o = h2_b[t];
        for (int c = 0; c < HC; c++) o = fmaf(qbuf[c], h2_w[c * 24 + t], o);
        out[((size_t)b * 24 + t) * 128 + n] = o;
    }
}

extern "C" void kernel_launch(void* const* d_in, const int* in_sizes, int n_in,
                              void* d_out, int out_size, void* d_ws, size_t ws_size,
                              hipStream_t stream) {
    const float* x      = (const float*)d_in[0];
    const float* in_w   = (const float*)d_in[1];
    const float* in_b   = (const float*)d_in[2];
    const float* pw_in  = (const float*)d_in[3];
    const float* dw_w   = (const float*)d_in[4];
    const float* pw_out = (const float*)d_in[5];
    const float* gn_g   = (const float*)d_in[6];
    const float* gn_b   = (const float*)d_in[7];
    const float* skip_w = (const float*)d_in[8];
    const float* ln_g   = (const float*)d_in[9];
    const float* ln_b   = (const float*)d_in[10];
    const float* h1_w   = (const float*)d_in[11];
    const float* h1_b   = (const float*)d_in[12];
    const float* h2_w   = (const float*)d_in[13];
    const float* h2_b   = (const float*)d_in[14];
    float* out = (float*)d_out;
    float* ws  = (float*)d_ws;

    tcn_setup<<<NL, 256, 0, stream>>>(pw_in, pw_out, gn_g, gn_b, ws);

    tcn_main<<<1024, 256, 0, stream>>>(x, in_w, in_b, dw_w, pw_out, skip_w,
                                       ln_g, ln_b, h1_w, h1_b, h2_w, h2_b, ws, out);
}

// Round 13
// 1242.423 us; speedup vs baseline: 2.3836x; 1.1178x over previous
//
#include <hip/hip_runtime.h>
#include <hip/hip_fp16.h>
#include <math.h>

#define TT 256
#define HC 128
#define HB 64
#define NL 8

// ---- ws layout ----
// uint view [0, 65536): packed fp16 weights, 8192 per layer:
//   [L*8192 + c*32 + o2]       = (W[c][2o2], W[c][2o2+1])   u-phase, pk_fma layout
//                                 (W = g_prev-folded pw_in^T)
//   [L*8192 + 4096 + c*32 + k] = (Po[c][2k], Po[c][2k+1])   s-phase (Po = pw_out)
// float view: Pb @65536, Pg @66048, Gp @66560, Bp @67584
#define WS_PB  65536
#define WS_PG  66048
#define WS_GP  66560
#define WS_BP  67584

typedef _Float16 h2vec __attribute__((ext_vector_type(2)));

__device__ __forceinline__ float fdot2(unsigned a, unsigned b, float c) {
#if __has_builtin(__builtin_amdgcn_fdot2)
    return __builtin_amdgcn_fdot2(__builtin_bit_cast(h2vec, a),
                                  __builtin_bit_cast(h2vec, b), c, false);
#else
    __half2 ah = __builtin_bit_cast(__half2, a);
    __half2 bh = __builtin_bit_cast(__half2, b);
    c = fmaf(__low2float(ah), __low2float(bh), c);
    return fmaf(__high2float(ah), __high2float(bh), c);
#endif
}

__device__ __forceinline__ float fast_tanh(float x) {
    float e = __expf(2.f * fabsf(x));
    float r = 1.f - 2.f / (1.f + e);
    return copysignf(r, x);
}
__device__ __forceinline__ float fast_sig(float x) {
    return 1.f / (1.f + __expf(-x));
}
__device__ __forceinline__ unsigned packh2(float a, float b) {
    __half2 h = __floats2half2_rn(a, b);
    return __builtin_bit_cast(unsigned, h);
}
__device__ __forceinline__ float loh(unsigned u) {
    return __low2float(__builtin_bit_cast(__half2, u));
}
__device__ __forceinline__ float hih(unsigned u) {
    return __high2float(__builtin_bit_cast(__half2, u));
}

__global__ __launch_bounds__(256)
void tcn_setup(const float* __restrict__ pw_in, const float* __restrict__ pw_out,
               const float* __restrict__ gn_g, const float* __restrict__ gn_b,
               float* __restrict__ ws) {
    const int i = blockIdx.x;      // layer
    const int tid = threadIdx.x;   // 256 threads
    unsigned* WP = (unsigned*)ws;
    float* Pb = ws + WS_PB;
    float* Pg = ws + WS_PG;
    float* Gp = ws + WS_GP;
    float* Bp = ws + WS_BP;

    if (tid < HC) {
        float g  = (i == 0) ? 1.f : gn_g[(i - 1) * HC + tid];
        float bb = (i == 0) ? 0.f : gn_b[(i - 1) * HC + tid];
        Gp[i * HC + tid] = g;
        Bp[i * HC + tid] = bb;
    }
    // u-phase weights (pk_fma layout): Wu[c*32+o2] = (pw_in[i][2o2][c]*g[c], pw_in[i][2o2+1][c]*g[c])
    for (int e = tid; e < 4096; e += 256) {
        int c = e >> 5, o2 = e & 31;
        float g = (i == 0) ? 1.f : gn_g[(i - 1) * HC + c];
        float w0 = pw_in[((size_t)i * HB + 2 * o2) * HC + c] * g;
        float w1 = pw_in[((size_t)i * HB + 2 * o2 + 1) * HC + c] * g;
        WP[(size_t)i * 8192 + e] = packh2(w0, w1);
    }
    // s-phase weights: Pp[c*32+k] = (pw_out[i][c][2k], pw_out[i][c][2k+1])
    for (int e = tid; e < 4096; e += 256) {
        int c = e >> 5, k = e & 31;
        float w0 = pw_out[((size_t)i * HC + c) * HB + 2 * k];
        float w1 = pw_out[((size_t)i * HC + c) * HB + 2 * k + 1];
        WP[(size_t)i * 8192 + 4096 + e] = packh2(w0, w1);
    }
    if (tid < HB) {
        float pb = 0.f, pg = 0.f;
        for (int c = 0; c < HC; c++) {
            float w = pw_in[((size_t)i * HB + tid) * HC + c];
            float gc = (i == 0) ? 1.f : gn_g[(i - 1) * HC + c];
            float bc = (i == 0) ? 0.f : gn_b[(i - 1) * HC + c];
            pb += bc * w;
            pg += gc * w;
        }
        Pb[i * HB + tid] = pb;
        Pg[i * HB + tid] = pg;
    }
}

// STATIC LDS: wlds 32768 + haloU 6336 + sLast 4096 + red 64 = 43264 B (2 blocks/CU, r12-proven)
// __launch_bounds__(256,2): empirically pins allocator at 128 VGPRs (r4/r6);
// peak live set is now ~116 (z2[64] + half2 acc2[32] + temps) -> fits, no spill.
__global__ __launch_bounds__(256, 2)
void tcn_main(const float* __restrict__ x, const float* __restrict__ in_w,
              const float* __restrict__ in_b, const float* __restrict__ dw_w,
              const float* __restrict__ pw_out, const float* __restrict__ skip_w,
              const float* __restrict__ ln_g, const float* __restrict__ ln_b,
              const float* __restrict__ h1_w, const float* __restrict__ h1_b,
              const float* __restrict__ h2_w, const float* __restrict__ h2_b,
              const float* __restrict__ ws, float* __restrict__ out) {
    __shared__ unsigned wlds[8192];     // [0,4096) Wu, [4096,8192) Pp for current layer
    __shared__ unsigned haloU[48 * 33]; // packed (u[k],u[32+k]) halo rows
    __shared__ float sLast[NL * HC];
    __shared__ float red[16];
    // head/last-layer buffers union haloU (halo dead by the time they're used)
    unsigned* wb2u = haloU;                   // 32 uints: last-layer packed w2
    float* hbuf = (float*)(haloU + 64);       // 128 floats
    float* qbuf = hbuf + 128;                 // 128 floats

    const float* Pb = ws + WS_PB;
    const float* Pg = ws + WS_PG;
    const float* Gp = ws + WS_GP;
    const float* Bp = ws + WS_BP;
    const unsigned* WP = (const unsigned*)ws;

    const int t = threadIdx.x;     // time index, 0..255
    const int bn = blockIdx.x;     // sample
    const int b = bn >> 7, n = bn & 127;
    const int lane = t & 63;
    const int wv = t >> 6;

    // residual state fully register-resident: z2[p] = (ch 2p, ch 2p+1), fp16
    unsigned z2[64];

    // ---------- phase 0: input projection  z[c] = x[b,t,n,:] @ in_w + in_b
    {
        const float* xp = x + (((size_t)b * TT + t) * 128 + n) * 16;
        float xr[16];
#pragma unroll
        for (int d = 0; d < 16; d++) xr[d] = xp[d];
#pragma unroll
        for (int c = 0; c < HC; c += 2) {
            float a0 = in_b[c], a1 = in_b[c + 1];
#pragma unroll
            for (int d = 0; d < 16; d++) {
                a0 = fmaf(xr[d], in_w[d * HC + c], a0);
                a1 = fmaf(xr[d], in_w[d * HC + c + 1], a1);
            }
            z2[c >> 1] = packh2(a0, a1);
        }
    }

    float m_s = 0.f, r_s = 1.f;   // deferred groupnorm scalars

#pragma unroll 1
    for (int L = 0; L < NL; L++) {
        const int dil = 1 << (L & 3);
        const bool lastL = (L == NL - 1);
        const bool active = (!lastL) || (wv == 3);

        // ---------- stage this layer's weights into LDS (all threads)
        {
            const uint4* src = (const uint4*)(WP + (size_t)L * 8192);
            uint4* dst = (uint4*)wlds;
#pragma unroll
            for (int i = 0; i < 8; i++) dst[t + 256 * i] = src[t + 256 * i];
        }
        __syncthreads();   // B0: weights staged

        // ---------- u-phase: packed fp16 accumulation (v_pk_fma_f16)
        // acc2[j] = (u[2j], u[2j+1]); then repack as puw[k] = (u[k], u[32+k])
        unsigned puw[32];
        if (active) {
            __half2 acc2[32];
            const __half2 zero2 = __floats2half2_rn(0.f, 0.f);
#pragma unroll
            for (int j = 0; j < 32; j++) acc2[j] = zero2;
#pragma unroll 2
            for (int p = 0; p < 64; p++) {
                __half2 zh = __builtin_bit_cast(__half2, z2[p]);
                __half2 zlo = __half2half2(__low2half(zh));
                __half2 zhi = __half2half2(__high2half(zh));
                const uint4* r0 = (const uint4*)(wlds + (2 * p) * 32);
                const uint4* r1 = (const uint4*)(wlds + (2 * p + 1) * 32);
#pragma unroll
                for (int o8 = 0; o8 < 8; o8++) {
                    uint4 q0 = r0[o8];
                    acc2[4 * o8 + 0] = __hfma2(zlo, __builtin_bit_cast(__half2, q0.x), acc2[4 * o8 + 0]);
                    acc2[4 * o8 + 1] = __hfma2(zlo, __builtin_bit_cast(__half2, q0.y), acc2[4 * o8 + 1]);
                    acc2[4 * o8 + 2] = __hfma2(zlo, __builtin_bit_cast(__half2, q0.z), acc2[4 * o8 + 2]);
                    acc2[4 * o8 + 3] = __hfma2(zlo, __builtin_bit_cast(__half2, q0.w), acc2[4 * o8 + 3]);
                }
#pragma unroll
                for (int o8 = 0; o8 < 8; o8++) {
                    uint4 q1 = r1[o8];
                    acc2[4 * o8 + 0] = __hfma2(zhi, __builtin_bit_cast(__half2, q1.x), acc2[4 * o8 + 0]);
                    acc2[4 * o8 + 1] = __hfma2(zhi, __builtin_bit_cast(__half2, q1.y), acc2[4 * o8 + 1]);
                    acc2[4 * o8 + 2] = __hfma2(zhi, __builtin_bit_cast(__half2, q1.z), acc2[4 * o8 + 2]);
                    acc2[4 * o8 + 3] = __hfma2(zhi, __builtin_bit_cast(__half2, q1.w), acc2[4 * o8 + 3]);
                }
            }
            float mr = m_s * r_s;
#pragma unroll
            for (int k = 0; k < 32; k++) {
                const int j = k >> 1;
                float va = (k & 1) ? __high2float(acc2[j])      : __low2float(acc2[j]);
                float vb = (k & 1) ? __high2float(acc2[16 + j]) : __low2float(acc2[16 + j]);
                float ua = fmaf(r_s, va, Pb[L * HB + k]      - mr * Pg[L * HB + k]);
                float ub = fmaf(r_s, vb, Pb[L * HB + 32 + k] - mr * Pg[L * HB + 32 + k]);
                puw[k] = packh2(ua, ub);
            }
            // halo publish: waves 0..2 only (wave 3 rows are never read)
            if (wv < 3 && lane >= 48) {
                int hr = wv * 16 + (lane - 48);
#pragma unroll
                for (int k = 0; k < 32; k++) haloU[hr * 33 + k] = puw[k];
            }
        }
        __syncthreads();   // B1: halo ready

        // ---------- conv + gating, IN PLACE: puw[k] (u[k],u[32+k]) -> (w[2k],w[2k+1])
        if (active) {
            const float* dwl = dw_w + (size_t)L * 128 * 3;
            const int d1 = dil, d2 = 2 * dil;
#pragma unroll
            for (int k = 0; k < 32; k++) {
                unsigned pk = puw[k];
                unsigned p1 = __shfl_up(pk, d1);
                unsigned p2 = __shfl_up(pk, d2);
                if (lane < d1) {
                    int tau = t - d1;
                    p1 = (tau < 0) ? 0u : haloU[((tau >> 6) * 16 + (tau & 63) - 48) * 33 + k];
                }
                if (lane < d2) {
                    int tau = t - d2;
                    p2 = (tau < 0) ? 0u : haloU[((tau >> 6) * 16 + (tau & 63) - 48) * 33 + k];
                }
                float uf = loh(pk), ug = hih(pk);
                float m1f = loh(p1), m1g = hih(p1);
                float m2f = loh(p2), m2g = hih(p2);
                float f0 = m2f * dwl[(2 * k) * 3 + 0] + m1f * dwl[(2 * k) * 3 + 1] + uf * dwl[(2 * k) * 3 + 2];
                float f1 = m2f * dwl[(2 * k + 1) * 3 + 0] + m1f * dwl[(2 * k + 1) * 3 + 1] + uf * dwl[(2 * k + 1) * 3 + 2];
                float g0 = m2g * dwl[(64 + 2 * k) * 3 + 0] + m1g * dwl[(64 + 2 * k) * 3 + 1] + ug * dwl[(64 + 2 * k) * 3 + 2];
                float g1 = m2g * dwl[(64 + 2 * k + 1) * 3 + 0] + m1g * dwl[(64 + 2 * k + 1) * 3 + 1] + ug * dwl[(64 + 2 * k + 1) * 3 + 2];
                puw[k] = packh2(fast_tanh(f0) * fast_sig(g0), fast_tanh(f1) * fast_sig(g1));
            }
        }

        if (!lastL) {
            // ---------- s-phase: s_feat via dot2, residual update (deferred GN), stats
            float s1 = 0.f, s2 = 0.f;
            const float mr = m_s * r_s;
            const float* gp = Gp + L * HC;
            const float* bp = Bp + L * HC;
#pragma unroll 2
            for (int cp = 0; cp < 64; cp++) {
                const int c = 2 * cp;
                float a0 = 0.f, a1 = 0.f;
                const uint4* r0 = (const uint4*)(wlds + 4096 + c * 32);
                const uint4* r1 = (const uint4*)(wlds + 4096 + (c + 1) * 32);
#pragma unroll
                for (int k4 = 0; k4 < 8; k4++) {
                    uint4 q0 = r0[k4], q1 = r1[k4];
                    a0 = fdot2(puw[4 * k4 + 0], q0.x, a0);
                    a0 = fdot2(puw[4 * k4 + 1], q0.y, a0);
                    a0 = fdot2(puw[4 * k4 + 2], q0.z, a0);
                    a0 = fdot2(puw[4 * k4 + 3], q0.w, a0);
                    a1 = fdot2(puw[4 * k4 + 0], q1.x, a1);
                    a1 = fdot2(puw[4 * k4 + 1], q1.y, a1);
                    a1 = fdot2(puw[4 * k4 + 2], q1.z, a1);
                    a1 = fdot2(puw[4 * k4 + 3], q1.w, a1);
                }
                if (t == TT - 1) {
                    sLast[L * HC + c] = a0;
                    sLast[L * HC + c + 1] = a1;
                }
                unsigned pz = z2[cp];
                float zo0 = loh(pz), zo1 = hih(pz);
                float g0 = gp[c], g1 = gp[c + 1];
                float zn0 = fmaf(zo0, r_s * g0, (bp[c]     - mr * g0) + a0);
                float zn1 = fmaf(zo1, r_s * g1, (bp[c + 1] - mr * g1) + a1);
                z2[cp] = packh2(zn0, zn1);
                s1 += zn0 + zn1;
                s2 += zn0 * zn0 + zn1 * zn1;
            }
#pragma unroll
            for (int off = 32; off; off >>= 1) {
                s1 += __shfl_xor(s1, off);
                s2 += __shfl_xor(s2, off);
            }
            if (lane == 0) { red[wv * 2] = s1; red[wv * 2 + 1] = s2; }
            __syncthreads();   // B2
            float S1 = red[0] + red[2] + red[4] + red[6];
            float S2 = red[1] + red[3] + red[5] + red[7];
            float mu = S1 * (1.f / 32768.f);
            float var = S2 * (1.f / 32768.f) - mu * mu;
            m_s = mu;
            r_s = rsqrtf(var + 1e-5f);
        } else {
            // last layer: only t==255's gated output matters; parallelize its s-row
            if (t == TT - 1) {
#pragma unroll
                for (int k = 0; k < 32; k++) wb2u[k] = puw[k];
            }
            __syncthreads();   // B2: wb2u ready
            if (t < HC) {
                float a = 0.f;
#pragma unroll
                for (int k = 0; k < 32; k++)
                    a = fdot2(wb2u[k], wlds[4096 + t * 32 + k], a);
                sLast[(NL - 1) * HC + t] = a;
            }
            __syncthreads();   // B3: sLast complete
        }
    }

    // ---------- head: h_last = sum_i skip_w[i] @ sLast[i]; LN; MLP
    float hl = 0.f;
    if (t < HC) {
        for (int i = 0; i < NL; i++) {
            const float4* swr = (const float4*)(skip_w + (((size_t)i * HC) + t) * HC);
            const float* sl = sLast + i * HC;
#pragma unroll 4
            for (int c4 = 0; c4 < 32; c4++) {
                float4 sw = swr[c4];
                hl += sw.x * sl[4 * c4] + sw.y * sl[4 * c4 + 1] + sw.z * sl[4 * c4 + 2] + sw.w * sl[4 * c4 + 3];
            }
        }
        hbuf[t] = hl;
    }
    __syncthreads();
    if (t < 64) {
        float v0 = hbuf[t], v1 = hbuf[t + 64];
        float a = v0 + v1, q = v0 * v0 + v1 * v1;
#pragma unroll
        for (int off = 32; off; off >>= 1) {
            a += __shfl_xor(a, off);
            q += __shfl_xor(q, off);
        }
        if (t == 0) {
            float mu = a * (1.f / 128.f);
            red[0] = mu;
            red[1] = rsqrtf(q * (1.f / 128.f) - mu * mu + 1e-5f);
        }
    }
    __syncthreads();
    {
        float mu = red[0], rs = red[1];
        if (t < HC) hbuf[t] = (hl - mu) * rs * ln_g[t] + ln_b[t];
    }
    __syncthreads();
    if (t < HC) {
        float q = h1_b[t];
        for (int c = 0; c < HC; c++) q = fmaf(hbuf[c], h1_w[c * HC + t], q);
        q = 0.5f * q * (1.f + erff(q * 0.70710678118654752f));
        qbuf[t] = q;
    }
    __syncthreads();
    if (t < 24) {
        float o = h2_b[t];
        for (int c = 0; c < HC; c++) o = fmaf(qbuf[c], h2_w[c * 24 + t], o);
        out[((size_t)b * 24 + t) * 128 + n] = o;
    }
}

extern "C" void kernel_launch(void* const* d_in, const int* in_sizes, int n_in,
                              void* d_out, int out_size, void* d_ws, size_t ws_size,
                              hipStream_t stream) {
    const float* x      = (const float*)d_in[0];
    const float* in_w   = (const float*)d_in[1];
    const float* in_b   = (const float*)d_in[2];
    const float* pw_in  = (const float*)d_in[3];
    const float* dw_w   = (const float*)d_in[4];
    const float* pw_out = (const float*)d_in[5];
    const float* gn_g   = (const float*)d_in[6];
    const float* gn_b   = (const float*)d_in[7];
    const float* skip_w = (const float*)d_in[8];
    const float* ln_g   = (const float*)d_in[9];
    const float* ln_b   = (const float*)d_in[10];
    const float* h1_w   = (const float*)d_in[11];
    const float* h1_b   = (const float*)d_in[12];
    const float* h2_w   = (const float*)d_in[13];
    const float* h2_b   = (const float*)d_in[14];
    float* out = (float*)d_out;
    float* ws  = (float*)d_ws;

    tcn_setup<<<NL, 256, 0, stream>>>(pw_in, pw_out, gn_g, gn_b, ws);

    tcn_main<<<1024, 256, 0, stream>>>(x, in_w, in_b, dw_w, pw_out, skip_w,
                                       ln_g, ln_b, h1_w, h1_b, h2_w, h2_b, ws, out);
}

// Round 14
// 1139.530 us; speedup vs baseline: 2.5988x; 1.0903x over previous
//
#include <hip/hip_runtime.h>
#include <hip/hip_fp16.h>
#include <math.h>

#define TT 256
#define HC 128
#define HB 64
#define NL 8

// ---- ws layout ----
// uint view [0, 65536): packed fp16 weights, 8192 per layer:
//   [L*8192 + c*32 + o2]       = (W[c][2o2], W[c][2o2+1])   u-phase, pk_fma layout
//   [L*8192 + 4096 + c*32 + k] = (Po[c][2k], Po[c][2k+1])   s-phase (Po = pw_out)
// float view: Pb @65536, Pg @66048, Gp @66560, Bp @67584
#define WS_PB  65536
#define WS_PG  66048
#define WS_GP  66560
#define WS_BP  67584

typedef _Float16 h2vec __attribute__((ext_vector_type(2)));

__device__ __forceinline__ float fdot2(unsigned a, unsigned b, float c) {
#if __has_builtin(__builtin_amdgcn_fdot2)
    return __builtin_amdgcn_fdot2(__builtin_bit_cast(h2vec, a),
                                  __builtin_bit_cast(h2vec, b), c, false);
#else
    __half2 ah = __builtin_bit_cast(__half2, a);
    __half2 bh = __builtin_bit_cast(__half2, b);
    c = fmaf(__low2float(ah), __low2float(bh), c);
    return fmaf(__high2float(ah), __high2float(bh), c);
#endif
}

__device__ __forceinline__ float fast_tanh(float x) {
    float e = __expf(2.f * fabsf(x));
    float r = 1.f - 2.f / (1.f + e);
    return copysignf(r, x);
}
__device__ __forceinline__ float fast_sig(float x) {
    return 1.f / (1.f + __expf(-x));
}
__device__ __forceinline__ unsigned packh2(float a, float b) {
    __half2 h = __floats2half2_rn(a, b);
    return __builtin_bit_cast(unsigned, h);
}
__device__ __forceinline__ float loh(unsigned u) {
    return __low2float(__builtin_bit_cast(__half2, u));
}
__device__ __forceinline__ float hih(unsigned u) {
    return __high2float(__builtin_bit_cast(__half2, u));
}

__global__ __launch_bounds__(256)
void tcn_setup(const float* __restrict__ pw_in, const float* __restrict__ pw_out,
               const float* __restrict__ gn_g, const float* __restrict__ gn_b,
               float* __restrict__ ws) {
    const int i = blockIdx.x;      // layer
    const int tid = threadIdx.x;   // 256 threads
    unsigned* WP = (unsigned*)ws;
    float* Pb = ws + WS_PB;
    float* Pg = ws + WS_PG;
    float* Gp = ws + WS_GP;
    float* Bp = ws + WS_BP;

    if (tid < HC) {
        float g  = (i == 0) ? 1.f : gn_g[(i - 1) * HC + tid];
        float bb = (i == 0) ? 0.f : gn_b[(i - 1) * HC + tid];
        Gp[i * HC + tid] = g;
        Bp[i * HC + tid] = bb;
    }
    // u-phase weights (pk_fma layout): Wu[c*32+o2] = (pw_in[i][2o2][c]*g[c], pw_in[i][2o2+1][c]*g[c])
    for (int e = tid; e < 4096; e += 256) {
        int c = e >> 5, o2 = e & 31;
        float g = (i == 0) ? 1.f : gn_g[(i - 1) * HC + c];
        float w0 = pw_in[((size_t)i * HB + 2 * o2) * HC + c] * g;
        float w1 = pw_in[((size_t)i * HB + 2 * o2 + 1) * HC + c] * g;
        WP[(size_t)i * 8192 + e] = packh2(w0, w1);
    }
    // s-phase weights: Pp[c*32+k] = (pw_out[i][c][2k], pw_out[i][c][2k+1])
    for (int e = tid; e < 4096; e += 256) {
        int c = e >> 5, k = e & 31;
        float w0 = pw_out[((size_t)i * HC + c) * HB + 2 * k];
        float w1 = pw_out[((size_t)i * HC + c) * HB + 2 * k + 1];
        WP[(size_t)i * 8192 + 4096 + e] = packh2(w0, w1);
    }
    if (tid < HB) {
        float pb = 0.f, pg = 0.f;
        for (int c = 0; c < HC; c++) {
            float w = pw_in[((size_t)i * HB + tid) * HC + c];
            float gc = (i == 0) ? 1.f : gn_g[(i - 1) * HC + c];
            float bc = (i == 0) ? 0.f : gn_b[(i - 1) * HC + c];
            pb += bc * w;
            pg += gc * w;
        }
        Pb[i * HB + tid] = pb;
        Pg[i * HB + tid] = pg;
    }
}

// STATIC LDS: wlds 32768 + haloU 6336 + sLast 4096 + red 64 = 43264 B
// RULE-#20 NOTE: every loop that indexes the register arrays z2/acc2/puw is
// FULLY unrolled — r12/r13's "#pragma unroll 2" left p/cp runtime, demoting
// z2[] to scratch (the 500MB WRITE_SIZE, VGPR_Count 68-88 mystery).
__global__ __launch_bounds__(256, 2)
void tcn_main(const float* __restrict__ x, const float* __restrict__ in_w,
              const float* __restrict__ in_b, const float* __restrict__ dw_w,
              const float* __restrict__ pw_out, const float* __restrict__ skip_w,
              const float* __restrict__ ln_g, const float* __restrict__ ln_b,
              const float* __restrict__ h1_w, const float* __restrict__ h1_b,
              const float* __restrict__ h2_w, const float* __restrict__ h2_b,
              const float* __restrict__ ws, float* __restrict__ out) {
    __shared__ unsigned wlds[8192];     // [0,4096) Wu, [4096,8192) Pp for current layer
    __shared__ unsigned haloU[48 * 33]; // packed (u[k],u[32+k]) halo rows
    __shared__ float sLast[NL * HC];
    __shared__ float red[16];
    // head/last-layer buffers union haloU (halo dead by the time they're used)
    unsigned* wb2u = haloU;                   // 32 uints: last-layer packed w2
    float* hbuf = (float*)(haloU + 64);       // 128 floats
    float* qbuf = hbuf + 128;                 // 128 floats

    const float* Pb = ws + WS_PB;
    const float* Pg = ws + WS_PG;
    const float* Gp = ws + WS_GP;
    const float* Bp = ws + WS_BP;
    const unsigned* WP = (const unsigned*)ws;

    const int t = threadIdx.x;     // time index, 0..255
    const int bn = blockIdx.x;     // sample
    const int b = bn >> 7, n = bn & 127;
    const int lane = t & 63;
    const int wv = t >> 6;

    // residual state fully register-resident: z2[p] = (ch 2p, ch 2p+1), fp16
    unsigned z2[64];

    // ---------- phase 0: input projection  z[c] = x[b,t,n,:] @ in_w + in_b
    {
        const float* xp = x + (((size_t)b * TT + t) * 128 + n) * 16;
        float xr[16];
#pragma unroll
        for (int d = 0; d < 16; d++) xr[d] = xp[d];
#pragma unroll
        for (int c = 0; c < HC; c += 2) {
            float a0 = in_b[c], a1 = in_b[c + 1];
#pragma unroll
            for (int d = 0; d < 16; d++) {
                a0 = fmaf(xr[d], in_w[d * HC + c], a0);
                a1 = fmaf(xr[d], in_w[d * HC + c + 1], a1);
            }
            z2[c >> 1] = packh2(a0, a1);
        }
    }

    float m_s = 0.f, r_s = 1.f;   // deferred groupnorm scalars

#pragma unroll 1
    for (int L = 0; L < NL; L++) {
        const int dil = 1 << (L & 3);
        const bool lastL = (L == NL - 1);
        const bool active = (!lastL) || (wv == 3);

        // ---------- stage this layer's weights into LDS (all threads)
        {
            const uint4* src = (const uint4*)(WP + (size_t)L * 8192);
            uint4* dst = (uint4*)wlds;
#pragma unroll
            for (int i = 0; i < 8; i++) dst[t + 256 * i] = src[t + 256 * i];
        }
        __syncthreads();   // B0: weights staged

        // ---------- u-phase: packed fp16 accumulation (v_pk_fma_f16)
        // acc2[j] = (u[2j], u[2j+1]); then repack as puw[k] = (u[k], u[32+k])
        unsigned puw[32];
        if (active) {
            __half2 acc2[32];
            const __half2 zero2 = __floats2half2_rn(0.f, 0.f);
#pragma unroll
            for (int j = 0; j < 32; j++) acc2[j] = zero2;
#pragma unroll
            for (int p = 0; p < 64; p++) {     // FULL unroll: z2[p] must stay static
                __half2 zh = __builtin_bit_cast(__half2, z2[p]);
                __half2 zlo = __half2half2(__low2half(zh));
                __half2 zhi = __half2half2(__high2half(zh));
                const uint4* r0 = (const uint4*)(wlds + (2 * p) * 32);
                const uint4* r1 = (const uint4*)(wlds + (2 * p + 1) * 32);
#pragma unroll
                for (int o8 = 0; o8 < 8; o8++) {
                    uint4 q0 = r0[o8];
                    acc2[4 * o8 + 0] = __hfma2(zlo, __builtin_bit_cast(__half2, q0.x), acc2[4 * o8 + 0]);
                    acc2[4 * o8 + 1] = __hfma2(zlo, __builtin_bit_cast(__half2, q0.y), acc2[4 * o8 + 1]);
                    acc2[4 * o8 + 2] = __hfma2(zlo, __builtin_bit_cast(__half2, q0.z), acc2[4 * o8 + 2]);
                    acc2[4 * o8 + 3] = __hfma2(zlo, __builtin_bit_cast(__half2, q0.w), acc2[4 * o8 + 3]);
                }
#pragma unroll
                for (int o8 = 0; o8 < 8; o8++) {
                    uint4 q1 = r1[o8];
                    acc2[4 * o8 + 0] = __hfma2(zhi, __builtin_bit_cast(__half2, q1.x), acc2[4 * o8 + 0]);
                    acc2[4 * o8 + 1] = __hfma2(zhi, __builtin_bit_cast(__half2, q1.y), acc2[4 * o8 + 1]);
                    acc2[4 * o8 + 2] = __hfma2(zhi, __builtin_bit_cast(__half2, q1.z), acc2[4 * o8 + 2]);
                    acc2[4 * o8 + 3] = __hfma2(zhi, __builtin_bit_cast(__half2, q1.w), acc2[4 * o8 + 3]);
                }
            }
            float mr = m_s * r_s;
#pragma unroll
            for (int k = 0; k < 32; k++) {
                const int j = k >> 1;
                float va = (k & 1) ? __high2float(acc2[j])      : __low2float(acc2[j]);
                float vb = (k & 1) ? __high2float(acc2[16 + j]) : __low2float(acc2[16 + j]);
                float ua = fmaf(r_s, va, Pb[L * HB + k]      - mr * Pg[L * HB + k]);
                float ub = fmaf(r_s, vb, Pb[L * HB + 32 + k] - mr * Pg[L * HB + 32 + k]);
                puw[k] = packh2(ua, ub);
            }
            // halo publish: waves 0..2 only (wave 3 rows are never read)
            if (wv < 3 && lane >= 48) {
                int hr = wv * 16 + (lane - 48);
#pragma unroll
                for (int k = 0; k < 32; k++) haloU[hr * 33 + k] = puw[k];
            }
        }
        __syncthreads();   // B1: halo ready

        // ---------- conv + gating, IN PLACE: puw[k] (u[k],u[32+k]) -> (w[2k],w[2k+1])
        if (active) {
            const float* dwl = dw_w + (size_t)L * 128 * 3;
            const int d1 = dil, d2 = 2 * dil;
#pragma unroll
            for (int k = 0; k < 32; k++) {
                unsigned pk = puw[k];
                unsigned p1 = __shfl_up(pk, d1);
                unsigned p2 = __shfl_up(pk, d2);
                if (lane < d1) {
                    int tau = t - d1;
                    p1 = (tau < 0) ? 0u : haloU[((tau >> 6) * 16 + (tau & 63) - 48) * 33 + k];
                }
                if (lane < d2) {
                    int tau = t - d2;
                    p2 = (tau < 0) ? 0u : haloU[((tau >> 6) * 16 + (tau & 63) - 48) * 33 + k];
                }
                float uf = loh(pk), ug = hih(pk);
                float m1f = loh(p1), m1g = hih(p1);
                float m2f = loh(p2), m2g = hih(p2);
                float f0 = m2f * dwl[(2 * k) * 3 + 0] + m1f * dwl[(2 * k) * 3 + 1] + uf * dwl[(2 * k) * 3 + 2];
                float f1 = m2f * dwl[(2 * k + 1) * 3 + 0] + m1f * dwl[(2 * k + 1) * 3 + 1] + uf * dwl[(2 * k + 1) * 3 + 2];
                float g0 = m2g * dwl[(64 + 2 * k) * 3 + 0] + m1g * dwl[(64 + 2 * k) * 3 + 1] + ug * dwl[(64 + 2 * k) * 3 + 2];
                float g1 = m2g * dwl[(64 + 2 * k + 1) * 3 + 0] + m1g * dwl[(64 + 2 * k + 1) * 3 + 1] + ug * dwl[(64 + 2 * k + 1) * 3 + 2];
                puw[k] = packh2(fast_tanh(f0) * fast_sig(g0), fast_tanh(f1) * fast_sig(g1));
            }
        }

        if (!lastL) {
            // ---------- s-phase: s_feat via dot2, residual update (deferred GN), stats
            float s1 = 0.f, s2 = 0.f;
            const float mr = m_s * r_s;
            const float* gp = Gp + L * HC;
            const float* bp = Bp + L * HC;
#pragma unroll
            for (int cp = 0; cp < 64; cp++) {  // FULL unroll: z2[cp] must stay static
                const int c = 2 * cp;
                float a0 = 0.f, a1 = 0.f;
                const uint4* r0 = (const uint4*)(wlds + 4096 + c * 32);
                const uint4* r1 = (const uint4*)(wlds + 4096 + (c + 1) * 32);
#pragma unroll
                for (int k4 = 0; k4 < 8; k4++) {
                    uint4 q0 = r0[k4], q1 = r1[k4];
                    a0 = fdot2(puw[4 * k4 + 0], q0.x, a0);
                    a0 = fdot2(puw[4 * k4 + 1], q0.y, a0);
                    a0 = fdot2(puw[4 * k4 + 2], q0.z, a0);
                    a0 = fdot2(puw[4 * k4 + 3], q0.w, a0);
                    a1 = fdot2(puw[4 * k4 + 0], q1.x, a1);
                    a1 = fdot2(puw[4 * k4 + 1], q1.y, a1);
                    a1 = fdot2(puw[4 * k4 + 2], q1.z, a1);
                    a1 = fdot2(puw[4 * k4 + 3], q1.w, a1);
                }
                if (t == TT - 1) {
                    sLast[L * HC + c] = a0;
                    sLast[L * HC + c + 1] = a1;
                }
                unsigned pz = z2[cp];
                float zo0 = loh(pz), zo1 = hih(pz);
                float g0 = gp[c], g1 = gp[c + 1];
                float zn0 = fmaf(zo0, r_s * g0, (bp[c]     - mr * g0) + a0);
                float zn1 = fmaf(zo1, r_s * g1, (bp[c + 1] - mr * g1) + a1);
                z2[cp] = packh2(zn0, zn1);
                s1 += zn0 + zn1;
                s2 += zn0 * zn0 + zn1 * zn1;
            }
#pragma unroll
            for (int off = 32; off; off >>= 1) {
                s1 += __shfl_xor(s1, off);
                s2 += __shfl_xor(s2, off);
            }
            if (lane == 0) { red[wv * 2] = s1; red[wv * 2 + 1] = s2; }
            __syncthreads();   // B2
            float S1 = red[0] + red[2] + red[4] + red[6];
            float S2 = red[1] + red[3] + red[5] + red[7];
            float mu = S1 * (1.f / 32768.f);
            float var = S2 * (1.f / 32768.f) - mu * mu;
            m_s = mu;
            r_s = rsqrtf(var + 1e-5f);
        } else {
            // last layer: only t==255's gated output matters; parallelize its s-row
            if (t == TT - 1) {
#pragma unroll
                for (int k = 0; k < 32; k++) wb2u[k] = puw[k];
            }
            __syncthreads();   // B2: wb2u ready
            if (t < HC) {
                float a = 0.f;
#pragma unroll
                for (int k = 0; k < 32; k++)
                    a = fdot2(wb2u[k], wlds[4096 + t * 32 + k], a);
                sLast[(NL - 1) * HC + t] = a;
            }
            __syncthreads();   // B3: sLast complete
        }
    }

    // ---------- head: h_last = sum_i skip_w[i] @ sLast[i]; LN; MLP
    float hl = 0.f;
    if (t < HC) {
        for (int i = 0; i < NL; i++) {
            const float4* swr = (const float4*)(skip_w + (((size_t)i * HC) + t) * HC);
            const float* sl = sLast + i * HC;
#pragma unroll 4
            for (int c4 = 0; c4 < 32; c4++) {
                float4 sw = swr[c4];
                hl += sw.x * sl[4 * c4] + sw.y * sl[4 * c4 + 1] + sw.z * sl[4 * c4 + 2] + sw.w * sl[4 * c4 + 3];
            }
        }
        hbuf[t] = hl;
    }
    __syncthreads();
    if (t < 64) {
        float v0 = hbuf[t], v1 = hbuf[t + 64];
        float a = v0 + v1, q = v0 * v0 + v1 * v1;
#pragma unroll
        for (int off = 32; off; off >>= 1) {
            a += __shfl_xor(a, off);
            q += __shfl_xor(q, off);
        }
        if (t == 0) {
            float mu = a * (1.f / 128.f);
            red[0] = mu;
            red[1] = rsqrtf(q * (1.f / 128.f) - mu * mu + 1e-5f);
        }
    }
    __syncthreads();
    {
        float mu = red[0], rs = red[1];
        if (t < HC) hbuf[t] = (hl - mu) * rs * ln_g[t] + ln_b[t];
    }
    __syncthreads();
    if (t < HC) {
        float q = h1_b[t];
        for (int c = 0; c < HC; c++) q = fmaf(hbuf[c], h1_w[c * HC + t], q);
        q = 0.5f * q * (1.f + erff(q * 0.70710678118654752f));
        qbuf[t] = q;
    }
    __syncthreads();
    if (t < 24) {
        float o = h2_b[t];
        for (int c = 0; c < HC; c++) o = fmaf(qbuf[c], h2_w[c * 24 + t], o);
        out[((size_t)b * 24 + t) * 128 + n] = o;
    }
}

extern "C" void kernel_launch(void* const* d_in, const int* in_sizes, int n_in,
                              void* d_out, int out_size, void* d_ws, size_t ws_size,
                              hipStream_t stream) {
    const float* x      = (const float*)d_in[0];
    const float* in_w   = (const float*)d_in[1];
    const float* in_b   = (const float*)d_in[2];
    const float* pw_in  = (const float*)d_in[3];
    const float* dw_w   = (const float*)d_in[4];
    const float* pw_out = (const float*)d_in[5];
    const float* gn_g   = (const float*)d_in[6];
    const float* gn_b   = (const float*)d_in[7];
    const float* skip_w = (const float*)d_in[8];
    const float* ln_g   = (const float*)d_in[9];
    const float* ln_b   = (const float*)d_in[10];
    const float* h1_w   = (const float*)d_in[11];
    const float* h1_b   = (const float*)d_in[12];
    const float* h2_w   = (const float*)d_in[13];
    const float* h2_b   = (const float*)d_in[14];
    float* out = (float*)d_out;
    float* ws  = (float*)d_ws;

    tcn_setup<<<NL, 256, 0, stream>>>(pw_in, pw_out, gn_g, gn_b, ws);

    tcn_main<<<1024, 256, 0, stream>>>(x, in_w, in_b, dw_w, pw_out, skip_w,
                                       ln_g, ln_b, h1_w, h1_b, h2_w, h2_b, ws, out);
}